// Round 10
// baseline (184.635 us; speedup 1.0000x reference)
//
#include <hip/hip_runtime.h>
#include <hip/hip_bf16.h>

typedef __attribute__((ext_vector_type(4))) float f32x4;
typedef __attribute__((ext_vector_type(8))) short short8v;
typedef __attribute__((ext_vector_type(8))) unsigned short ushort8v;

#define T_ROWS 16384
#define H_DIM  4096
#define E_NUM  64
#define TOPK   8
#define KC     64
#define NCH    (H_DIM / KC)       // 64 chunks
#define WIMG   16384              // bytes per W chunk image (hi+lo planes)
#define MASK_OFF ((size_t)NCH * WIMG)

__device__ __forceinline__ unsigned short f2bf(float f) {
    unsigned int u = __float_as_uint(f);
    unsigned int r = (u + 0x7fffu + ((u >> 16) & 1u)) >> 16;  // RNE
    return (unsigned short)r;
}
__device__ __forceinline__ float bf2f(unsigned short h) {
    return __uint_as_float(((unsigned int)h) << 16);
}

// ---- prep: per-chunk swizzled images of W (bf16 hi/lo) + allowed-mask ----
// for ch in [0,64): 16KB = [plane hi|lo 8KB][row 0..63][128B xor-swizzled]
__global__ __launch_bounds__(256) void prep_w(
    const float* __restrict__ W, unsigned short* __restrict__ WS,
    const int* __restrict__ ids, int nids)
{
    const int g     = blockIdx.x * 256 + threadIdx.x;   // one 16B group
    const int byteo = g * 16;
    const int ch    = byteo >> 14;
    const int rem   = byteo & 16383;
    const int plane = rem >> 13;
    const int rb2   = rem & 8191;
    const int row   = rb2 >> 7;
    const int sb    = rb2 & 127;
    const int bc    = sb ^ ((row & 7) << 4);
    const float* src = W + (size_t)row * H_DIM + ch * KC + (bc >> 1);
    ushort8v o;
#pragma unroll
    for (int j = 0; j < 8; ++j) {
        const float f = src[j];
        const unsigned short hb = f2bf(f);
        o[j] = (plane == 0) ? hb : f2bf(f - bf2f(hb));
    }
    *(ushort8v*)((char*)WS + byteo) = o;

    if (blockIdx.x == 0 && threadIdx.x == 0) {
        unsigned long long mb = 0;
        for (int t = 0; t < nids; ++t) {
            const int e = ids[t];
            if (e >= 0 && e < E_NUM) mb |= (1ull << e);
        }
        *(unsigned long long*)((char*)WS + MASK_OFF) = mb;
    }
}

// ---- main: grid 1024 x 256 thr = 4 waves; block = 16 rows; wave w = experts
// [w*16, w*16+16) over the FULL K chain. No LDS / no barriers in the loop. ----
__global__ __launch_bounds__(256) void router_main(
    const float* __restrict__ X, const unsigned short* __restrict__ WS,
    float* __restrict__ out)
{
    const int tid  = threadIdx.x;
    const int lane = tid & 63;
    const int w    = tid >> 6;          // expert quarter
    const int rb   = blockIdx.x * 16;
    const int fr   = lane & 15;
    const int fq   = lane >> 4;

    const float* xrow = X + (size_t)(rb + fr) * H_DIM + fq * 8;
    const char*  wimg = (const char*)WS;
    const int    brow = w * 16 + fr;
    const int    sw   = (brow & 7) << 4;
    const int    bb0  = brow * 128 + ((fq * 16) ^ sw);        // ks=0
    const int    bb1  = brow * 128 + ((64 + fq * 16) ^ sw);   // ks=1

    f32x4 acc = {0.f, 0.f, 0.f, 0.f};

    // named depth-1 double-buffer registers (parity A/B, static indexing)
    float4  xA0, xA1, xA2, xA3, xB0, xB1, xB2, xB3;
    short8v hA0, lA0, hA1, lA1, hB0, lB0, hB1, lB1;

#define LOADCH(S, CH) do {                                   \
        const float* xp_ = xrow + (CH) * KC;                 \
        x##S##0 = *(const float4*)(xp_);                     \
        x##S##1 = *(const float4*)(xp_ + 4);                 \
        x##S##2 = *(const float4*)(xp_ + 32);                \
        x##S##3 = *(const float4*)(xp_ + 36);                \
        const char* wi_ = wimg + (size_t)(CH) * WIMG;        \
        h##S##0 = *(const short8v*)(wi_ + bb0);              \
        l##S##0 = *(const short8v*)(wi_ + 8192 + bb0);       \
        h##S##1 = *(const short8v*)(wi_ + bb1);              \
        l##S##1 = *(const short8v*)(wi_ + 8192 + bb1);       \
    } while (0)

    auto ksstep = [&](float4 a0, float4 a1, short8v bh, short8v bl) {
        float v[8] = {a0.x, a0.y, a0.z, a0.w, a1.x, a1.y, a1.z, a1.w};
        short8v ah, al;
#pragma unroll
        for (int j = 0; j < 8; ++j) {
            const unsigned short hb = f2bf(v[j]);
            ah[j] = (short)hb;
            al[j] = (short)f2bf(v[j] - bf2f(hb));
        }
        acc = __builtin_amdgcn_mfma_f32_16x16x32_bf16(ah, bh, acc, 0, 0, 0);
        acc = __builtin_amdgcn_mfma_f32_16x16x32_bf16(ah, bl, acc, 0, 0, 0);
        acc = __builtin_amdgcn_mfma_f32_16x16x32_bf16(al, bh, acc, 0, 0, 0);
    };

#define BODY(CH, CUR, NXT) do {                              \
        if ((CH) + 1 < NCH) { LOADCH(NXT, (CH) + 1); }       \
        __builtin_amdgcn_sched_barrier(0);                   \
        ksstep(x##CUR##0, x##CUR##1, h##CUR##0, l##CUR##0);  \
        ksstep(x##CUR##2, x##CUR##3, h##CUR##1, l##CUR##1);  \
    } while (0)

    LOADCH(A, 0);
    for (int ch = 0; ch < NCH; ch += 2) {
        BODY(ch,     A, B);
        BODY(ch + 1, B, A);
    }
#undef BODY
#undef LOADCH

    // ---- scoreboard (one barrier total), wave 0 runs the verified epilogue ----
    __shared__ float sm[16 * 68];
#pragma unroll
    for (int j = 0; j < 4; ++j) {
        sm[(fq * 4 + j) * 68 + w * 16 + fr] = acc[j];
    }
    __syncthreads();
    if (w != 0) return;

    const unsigned long long mbits =
        *(const unsigned long long*)(wimg + MASK_OFF);

    float* o_log = out;
    float* o_rw  = out + (size_t)T_ROWS * E_NUM;
    float* o_se  = o_rw + (size_t)T_ROWS * TOPK;

#pragma unroll
    for (int j = 0; j < 4; ++j) {
        const int row_l = fq * 4 + j;
        const int grow  = rb + row_l;
        float a0 = sm[row_l * 68 +  0 + fr];
        float a1 = sm[row_l * 68 + 16 + fr];
        float a2 = sm[row_l * 68 + 32 + fr];
        float a3 = sm[row_l * 68 + 48 + fr];
        float mv0 = ((mbits >> ( 0 + fr)) & 1) ? a0 : -10000.0f;
        float mv1 = ((mbits >> (16 + fr)) & 1) ? a1 : -10000.0f;
        float mv2 = ((mbits >> (32 + fr)) & 1) ? a2 : -10000.0f;
        float mv3 = ((mbits >> (48 + fr)) & 1) ? a3 : -10000.0f;
        o_log[(size_t)grow * 64 +  0 + fr] = mv0;
        o_log[(size_t)grow * 64 + 16 + fr] = mv1;
        o_log[(size_t)grow * 64 + 32 + fr] = mv2;
        o_log[(size_t)grow * 64 + 48 + fr] = mv3;

        float m = fmaxf(fmaxf(mv0, mv1), fmaxf(mv2, mv3));
#pragma unroll
        for (int off = 1; off < 16; off <<= 1) m = fmaxf(m, __shfl_xor(m, off));

        float tsum = 0.f, myv = 0.f;
        int   mye  = 0;
#pragma unroll
        for (int t = 0; t < TOPK; ++t) {
            float bv = mv0; int be = fr;
            if (mv1 > bv) { bv = mv1; be = 16 + fr; }
            if (mv2 > bv) { bv = mv2; be = 32 + fr; }
            if (mv3 > bv) { bv = mv3; be = 48 + fr; }
#pragma unroll
            for (int off = 1; off < 16; off <<= 1) {
                float ov = __shfl_xor(bv, off);
                int   oe = __shfl_xor(be, off);
                if (ov > bv || (ov == bv && oe < be)) { bv = ov; be = oe; }
            }
            const float pv = expf(bv - m);
            tsum += pv;
            if (fr == t) { myv = pv; mye = be; }
            if ((be & 15) == fr) {       // owner lane excludes winner
                const int bn = be >> 4;
                if      (bn == 0) mv0 = -3.4e38f;
                else if (bn == 1) mv1 = -3.4e38f;
                else if (bn == 2) mv2 = -3.4e38f;
                else              mv3 = -3.4e38f;
            }
        }
        if (fr < TOPK) {
            o_rw[(size_t)grow * TOPK + fr] = myv / tsum;
            o_se[(size_t)grow * TOPK + fr] = (float)mye;
        }
    }
}

extern "C" void kernel_launch(void* const* d_in, const int* in_sizes, int n_in,
                              void* d_out, int out_size, void* d_ws, size_t ws_size,
                              hipStream_t stream) {
    const float* X   = (const float*)d_in[0];
    const float* W   = (const float*)d_in[1];
    const int*   ids = (const int*)d_in[2];
    const int    nids = in_sizes[2];
    float* out = (float*)d_out;

    unsigned short* WS = (unsigned short*)d_ws;   // 1 MB W image + 8 B mask

    hipLaunchKernelGGL(prep_w, dim3(NCH * WIMG / 16 / 256), dim3(256), 0, stream,
                       W, WS, ids, nids);
    hipLaunchKernelGGL(router_main, dim3(T_ROWS / 16), dim3(256), 0, stream,
                       X, WS, out);
}

// Round 11
// 93.888 us; speedup vs baseline: 1.9665x; 1.9665x over previous
//
#include <hip/hip_runtime.h>
#include <hip/hip_bf16.h>

typedef __attribute__((ext_vector_type(16))) float f32x16;
typedef __attribute__((ext_vector_type(8))) short short8v;
typedef __attribute__((ext_vector_type(8))) unsigned short ushort8v;

#define T_ROWS 16384
#define H_DIM  4096
#define E_NUM  64
#define TOPK   8
#define MROWS  32               // rows per block
#define KC     128              // k-chunk
#define NCH    (H_DIM / KC)     // 32 chunks
#define WIMG   32768            // bytes per W chunk image (hi+lo planes)
#define MASK_OFF ((size_t)NCH * WIMG)

__device__ __forceinline__ unsigned short f2bf(float f) {
    unsigned int u = __float_as_uint(f);
    unsigned int r = (u + 0x7fffu + ((u >> 16) & 1u)) >> 16;  // RNE
    return (unsigned short)r;
}
__device__ __forceinline__ float bf2f(unsigned short h) {
    return __uint_as_float(((unsigned int)h) << 16);
}

// ---- prep: per-chunk swizzled images of W (bf16 hi/lo) + allowed-mask ----
// for ch in [0,32): 32KB = [plane hi|lo 16KB][row 0..63][256B, byte^((row&15)<<4)]
__global__ __launch_bounds__(256) void prep_w(
    const float* __restrict__ W, unsigned short* __restrict__ WS,
    const int* __restrict__ ids, int nids)
{
    const int g     = blockIdx.x * 256 + threadIdx.x;   // one 16B group
    const int byteo = g * 16;
    const int ch    = byteo >> 15;
    const int rem   = byteo & 32767;
    const int plane = rem >> 14;
    const int rb2   = rem & 16383;
    const int row   = rb2 >> 8;
    const int sb    = rb2 & 255;
    const int bc    = sb ^ ((row & 15) << 4);
    const float* src = W + (size_t)row * H_DIM + ch * KC + (bc >> 1);
    ushort8v o;
#pragma unroll
    for (int j = 0; j < 8; ++j) {
        const float f = src[j];
        const unsigned short hb = f2bf(f);
        o[j] = (plane == 0) ? hb : f2bf(f - bf2f(hb));
    }
    *(ushort8v*)((char*)WS + byteo) = o;

    if (blockIdx.x == 0 && threadIdx.x == 0) {
        unsigned long long mb = 0;
        for (int t = 0; t < nids; ++t) {
            const int e = ids[t];
            if (e >= 0 && e < E_NUM) mb |= (1ull << e);
        }
        *(unsigned long long*)((char*)WS + MASK_OFF) = mb;
    }
}

// ---- main: 512 thr = 8 waves; wave (cg=w&1, kh=w>>1) computes a 32x32
// partial (rows rb..rb+32 x experts cg*32..+32) over K-quarter kh, using
// mfma_f32_32x32x16_bf16 (half the LDS bytes per MAC vs 16x16x32). ----
__global__ __launch_bounds__(512, 2) void router_main(
    const float* __restrict__ X, const unsigned short* __restrict__ WS,
    float* __restrict__ out)
{
    const int tid  = threadIdx.x;
    const int lane = tid & 63;
    const int w    = tid >> 6;        // 0..7
    const int cg   = w & 1;           // experts half
    const int kh   = w >> 1;          // K quarter of the chunk
    const int rb   = blockIdx.x * MROWS;
    const int fr32 = lane & 31;
    const int fo   = lane >> 5;       // k-octet within k16

    __shared__ char LDSRAW[49152];
    char* XH = LDSRAW;                // 8 KB  [32][256B swizzled] bf16-hi
    char* XL = LDSRAW + 8192;         // 8 KB  bf16-lo
    char* WB = LDSRAW + 16384;        // 32 KB W image (hi 16K | lo 16K)

    // staging coords: X 8 f32/thread; W 4x16B/thread (linear copy of image)
    const int srow = tid >> 4;               // 0..31
    const int sc8  = (tid & 15) * 8;         // f32 col base
    const float* xg  = X + (size_t)(rb + srow) * H_DIM + sc8;
    const char*  wsg = (const char*)WS;
    const int xbyte = srow * 256 + ((sc8 * 2) ^ ((srow & 15) << 4));

    const int arow = fr32;
    const int brow = cg * 32 + fr32;
    const int asw  = (arow & 15) << 4;
    const int bsw  = (brow & 15) << 4;

    f32x16 acc;
#pragma unroll
    for (int r = 0; r < 16; ++r) acc[r] = 0.f;

    // ---- prologue: chunk-0 registers ----
    float4 px0 = *(const float4*)(xg);
    float4 px1 = *(const float4*)(xg + 4);
    uint4 pw0 = *(const uint4*)(wsg + 0 * 8192 + tid * 16);
    uint4 pw1 = *(const uint4*)(wsg + 1 * 8192 + tid * 16);
    uint4 pw2 = *(const uint4*)(wsg + 2 * 8192 + tid * 16);
    uint4 pw3 = *(const uint4*)(wsg + 3 * 8192 + tid * 16);

    for (int ch = 0; ch < NCH; ++ch) {
        __syncthreads();   // [A] previous compute done reading LDS
        // ---- stage: split X 8 f32 -> hi/lo, write; copy W regs -> LDS ----
        {
            float v[8] = {px0.x, px0.y, px0.z, px0.w, px1.x, px1.y, px1.z, px1.w};
            ushort8v hv, lv;
#pragma unroll
            for (int j = 0; j < 8; ++j) {
                const unsigned short hb = f2bf(v[j]);
                hv[j] = hb;
                lv[j] = f2bf(v[j] - bf2f(hb));
            }
            *(ushort8v*)(XH + xbyte) = hv;
            *(ushort8v*)(XL + xbyte) = lv;
        }
        *(uint4*)(WB + 0 * 8192 + tid * 16) = pw0;
        *(uint4*)(WB + 1 * 8192 + tid * 16) = pw1;
        *(uint4*)(WB + 2 * 8192 + tid * 16) = pw2;
        *(uint4*)(WB + 3 * 8192 + tid * 16) = pw3;
        __syncthreads();   // [B] tiles ready
        // ---- issue next chunk's global loads (land during compute+drain) ----
        if (ch + 1 < NCH) {
            const float* xn = xg + (ch + 1) * KC;
            px0 = *(const float4*)(xn);
            px1 = *(const float4*)(xn + 4);
            const char* wn = wsg + (size_t)(ch + 1) * WIMG;
            pw0 = *(const uint4*)(wn + 0 * 8192 + tid * 16);
            pw1 = *(const uint4*)(wn + 1 * 8192 + tid * 16);
            pw2 = *(const uint4*)(wn + 2 * 8192 + tid * 16);
            pw3 = *(const uint4*)(wn + 3 * 8192 + tid * 16);
        }
        // ---- compute: this wave's K-quarter = 2 k16-steps x 3 MFMA ----
#pragma unroll
        for (int ks = 0; ks < 2; ++ks) {
            const int kbyte = kh * 64 + ks * 32 + fo * 16;
            short8v ah = *(const short8v*)(XH + arow * 256 + (kbyte ^ asw));
            short8v al = *(const short8v*)(XL + arow * 256 + (kbyte ^ asw));
            short8v bh = *(const short8v*)(WB + brow * 256 + (kbyte ^ bsw));
            short8v bl = *(const short8v*)(WB + 16384 + brow * 256 + (kbyte ^ bsw));
            acc = __builtin_amdgcn_mfma_f32_32x32x16_bf16(ah, bh, acc, 0, 0, 0);
            acc = __builtin_amdgcn_mfma_f32_32x32x16_bf16(ah, bl, acc, 0, 0, 0);
            acc = __builtin_amdgcn_mfma_f32_32x32x16_bf16(al, bh, acc, 0, 0, 0);
        }
    }

    // ---- scoreboard: 4 kh-planes [4][32][68] f32, deterministic reduce ----
    __syncthreads();                       // all compute done
    float* sm = (float*)LDSRAW;            // 34.8 KB <= 48 KB
    // C/D layout (m74/m101-verified): col = lane&31, row = (r&3)+8*(r>>2)+4*(lane>>5)
#pragma unroll
    for (int r = 0; r < 16; ++r) {
        const int row = (r & 3) + 8 * (r >> 2) + 4 * fo;
        sm[(kh * 32 + row) * 68 + cg * 32 + fr32] = acc[r];
    }
    __syncthreads();
    if (w >= 2) return;                    // no barriers after this point

    const unsigned long long mbits =
        *(const unsigned long long*)((const char*)WS + MASK_OFF);

    const int fr = lane & 15;
    const int fq = lane >> 4;
    float* o_log = out;
    float* o_rw  = out + (size_t)T_ROWS * E_NUM;
    float* o_se  = o_rw + (size_t)T_ROWS * TOPK;

    // wave w handles rows w*16 .. w*16+15 with the value-verified epilogue
#pragma unroll
    for (int j = 0; j < 4; ++j) {
        const int row_l = w * 16 + fq * 4 + j;
        const int grow  = rb + row_l;
        float a0 = 0.f, a1 = 0.f, a2 = 0.f, a3 = 0.f;
#pragma unroll
        for (int p = 0; p < 4; ++p) {      // fixed-order kh reduction
            a0 += sm[(p * 32 + row_l) * 68 +  0 + fr];
            a1 += sm[(p * 32 + row_l) * 68 + 16 + fr];
            a2 += sm[(p * 32 + row_l) * 68 + 32 + fr];
            a3 += sm[(p * 32 + row_l) * 68 + 48 + fr];
        }
        float mv0 = ((mbits >> ( 0 + fr)) & 1) ? a0 : -10000.0f;
        float mv1 = ((mbits >> (16 + fr)) & 1) ? a1 : -10000.0f;
        float mv2 = ((mbits >> (32 + fr)) & 1) ? a2 : -10000.0f;
        float mv3 = ((mbits >> (48 + fr)) & 1) ? a3 : -10000.0f;
        o_log[(size_t)grow * 64 +  0 + fr] = mv0;
        o_log[(size_t)grow * 64 + 16 + fr] = mv1;
        o_log[(size_t)grow * 64 + 32 + fr] = mv2;
        o_log[(size_t)grow * 64 + 48 + fr] = mv3;

        float m = fmaxf(fmaxf(mv0, mv1), fmaxf(mv2, mv3));
#pragma unroll
        for (int off = 1; off < 16; off <<= 1) m = fmaxf(m, __shfl_xor(m, off));

        float tsum = 0.f, myv = 0.f;
        int   mye  = 0;
#pragma unroll
        for (int t = 0; t < TOPK; ++t) {
            float bv = mv0; int be = fr;
            if (mv1 > bv) { bv = mv1; be = 16 + fr; }
            if (mv2 > bv) { bv = mv2; be = 32 + fr; }
            if (mv3 > bv) { bv = mv3; be = 48 + fr; }
#pragma unroll
            for (int off = 1; off < 16; off <<= 1) {
                float ov = __shfl_xor(bv, off);
                int   oe = __shfl_xor(be, off);
                if (ov > bv || (ov == bv && oe < be)) { bv = ov; be = oe; }
            }
            const float pv = expf(bv - m);
            tsum += pv;
            if (fr == t) { myv = pv; mye = be; }
            if ((be & 15) == fr) {       // owner lane excludes winner
                const int bn = be >> 4;
                if      (bn == 0) mv0 = -3.4e38f;
                else if (bn == 1) mv1 = -3.4e38f;
                else if (bn == 2) mv2 = -3.4e38f;
                else              mv3 = -3.4e38f;
            }
        }
        if (fr < TOPK) {
            o_rw[(size_t)grow * TOPK + fr] = myv / tsum;
            o_se[(size_t)grow * TOPK + fr] = (float)mye;
        }
    }
}

extern "C" void kernel_launch(void* const* d_in, const int* in_sizes, int n_in,
                              void* d_out, int out_size, void* d_ws, size_t ws_size,
                              hipStream_t stream) {
    const float* X   = (const float*)d_in[0];
    const float* W   = (const float*)d_in[1];
    const int*   ids = (const int*)d_in[2];
    const int    nids = in_sizes[2];
    float* out = (float*)d_out;

    unsigned short* WS = (unsigned short*)d_ws;   // 1 MB W image + 8 B mask

    hipLaunchKernelGGL(prep_w, dim3(NCH * WIMG / 16 / 256), dim3(256), 0, stream,
                       W, WS, ids, nids);
    hipLaunchKernelGGL(router_main, dim3(T_ROWS / MROWS), dim3(512), 0, stream,
                       X, WS, out);
}